// Round 9
// baseline (127.029 us; speedup 1.0000x reference)
//
#include <hip/hip_runtime.h>
#include <hip/hip_bf16.h>

#define NN   8000
#define NE   64000
#define NE2  72000   // edges + self loops
#define NH   8
#define OC   512
#define HC   4096    // NH*OC
#define KIN  128
#define NOUT 512
#define YW   1024    // NH*KIN
#define MAXDEG 64    // in-degree = 1 + Binomial(64000,1/8000); P(>63) astronomically small
#define NEG_SLOPE 0.2f

// phase A: [0,128) W_gat->bf16 + v ; 128: zero cursors ; [129,257) W_lin transpose + beff partials
#define VSRC_NB   128
#define TRN_BASE  129
#define PHA_NB    257

// phase B: [0,64) Wc GEMM ; [64,346) edge fill ; 346: beff reduce ; [347,847) attn2
#define PB_GEMM_NB 64
#define FILL_BASE  64
#define RED_BID    346
#define ATT_BASE   347
#define PHB_NB     847

#define GEMM_NB   500   // 125 m-tiles x 4 n-tiles (64x128 out each)

using bf16 = __hip_bfloat16;
typedef float  f32x4  __attribute__((ext_vector_type(4)));
typedef __bf16 bf16x8 __attribute__((ext_vector_type(8)));

static __device__ __forceinline__ void gld_lds16(const bf16* g, bf16* l){
    __builtin_amdgcn_global_load_lds(
        (const __attribute__((address_space(1))) unsigned int*)g,
        (__attribute__((address_space(3))) unsigned int*)l, 16, 0, 0);
}

struct Acc24 { f32x4 a[2][4]; };

// ======= final-GEMM tile: 64x128, BK=64, XOR-swizzled LDS (both-sides), dbuf =======
static __device__ __forceinline__ void gemm64x128_bk64(
    const bf16* __restrict__ A, int lda, const bf16* __restrict__ BT, int ldb,
    int K, bf16* sA, bf16* sB, int tid, Acc24& acc)
{
    const int lane = tid & 63;
    const int w    = tid >> 6;
    const int wm   = w >> 1, wn = w & 1;
    const int m16  = lane & 15, q = lane >> 4;

    const int cA0 = tid,        cA1 = tid + 256;
    const int rA0 = cA0 >> 3,   jA0 = (cA0 & 7) ^ (rA0 & 7);
    const int rA1 = cA1 >> 3,   jA1 = (cA1 & 7) ^ (rA1 & 7);
    const size_t gA0 = (size_t)rA0 * lda + jA0 * 8;
    const size_t gA1 = (size_t)rA1 * lda + jA1 * 8;
    size_t gB[4]; int cB[4];
    #pragma unroll
    for (int u=0; u<4; ++u){
        int c = tid + 256*u;
        int r = c >> 3, j = (c & 7) ^ (r & 7);
        cB[u] = c;
        gB[u] = (size_t)r * ldb + j * 8;
    }

    #pragma unroll
    for (int i=0;i<2;++i)
        #pragma unroll
        for (int j=0;j<4;++j)
            #pragma unroll
            for (int r=0;r<4;++r) acc.a[i][j][r] = 0.f;

    gld_lds16(A  + gA0, sA + cA0*8);
    gld_lds16(A  + gA1, sA + cA1*8);
    #pragma unroll
    for (int u=0; u<4; ++u) gld_lds16(BT + gB[u], sB + cB[u]*8);
    __syncthreads();

    const int nIter = K / 64;
    for (int it = 0; it < nIter; ++it){
        const int cur = it & 1, nxt = cur ^ 1;
        bf16x8 af[2][2], bfr[4][2];
        #pragma unroll
        for (int ks=0; ks<2; ++ks){
            #pragma unroll
            for (int i=0;i<2;++i){
                int row = wm*32 + i*16 + m16;
                int p   = (ks*4 + q) ^ (row & 7);
                af[i][ks] = *(const bf16x8*)(const void*)(sA + cur*64*64 + row*64 + p*8);
            }
            #pragma unroll
            for (int j=0;j<4;++j){
                int row = wn*64 + j*16 + m16;
                int p   = (ks*4 + q) ^ (row & 7);
                bfr[j][ks] = *(const bf16x8*)(const void*)(sB + cur*128*64 + row*64 + p*8);
            }
        }
        if (it + 1 < nIter){
            const size_t ko = (size_t)(it+1) * 64;
            gld_lds16(A  + gA0 + ko, sA + nxt*64*64 + cA0*8);
            gld_lds16(A  + gA1 + ko, sA + nxt*64*64 + cA1*8);
            #pragma unroll
            for (int u=0; u<4; ++u) gld_lds16(BT + gB[u] + ko, sB + nxt*128*64 + cB[u]*8);
        }
        #pragma unroll
        for (int ks=0; ks<2; ++ks)
            #pragma unroll
            for (int i=0;i<2;++i)
                #pragma unroll
                for (int j=0;j<4;++j)
                    acc.a[i][j] = __builtin_amdgcn_mfma_f32_16x16x32_bf16(af[i][ks], bfr[j][ks], acc.a[i][j], 0, 0, 0);
        __syncthreads();
    }
}

// ================= phase A =================
// [0,128):   W_gat->bf16 (Wg) + v[k][h]   (float4 loads, ushort4 packed stores)
// 128:       zero cursors
// [129,257): WlT[o][c] = bf16(W_lin[c][o]) transpose + beff_part[b][o] partials
__global__ __launch_bounds__(256) void k_phaseA(
    const float* __restrict__ W_gat,
    const float* __restrict__ att_src, const float* __restrict__ att_dst,
    const float* __restrict__ W_lin, const float* __restrict__ b_gat,
    bf16* __restrict__ Wg, float* __restrict__ v,
    bf16* __restrict__ WlT, float* __restrict__ beff_part,
    int* __restrict__ cursors)
{
    __shared__ float tl[32][132];
    __shared__ float bg_s[32];
    const int bid = blockIdx.x;
    const int tid = threadIdx.x;

    if (bid < VSRC_NB){
        int k = bid;
        int lane = tid & 63, g = tid >> 6;
        for (int hh = g; hh < NH; hh += 4){
            const float* wp = W_gat + (size_t)k*HC + hh*OC;
            bf16*        wb = Wg    + (size_t)k*HC + hh*OC;
            const float* as = att_src + hh*OC;
            const float* ad = att_dst + hh*OC;
            float ss = 0.f, sd = 0.f;
            #pragma unroll
            for (int c0=0; c0<OC; c0+=256){
                float4 wv = *(const float4*)(wp + c0 + lane*4);
                float4 av = *(const float4*)(as + c0 + lane*4);
                float4 dv = *(const float4*)(ad + c0 + lane*4);
                bf16 b0=__float2bfloat16(wv.x), b1=__float2bfloat16(wv.y),
                     b2=__float2bfloat16(wv.z), b3=__float2bfloat16(wv.w);
                ushort4 pk;
                pk.x=*(unsigned short*)&b0; pk.y=*(unsigned short*)&b1;
                pk.z=*(unsigned short*)&b2; pk.w=*(unsigned short*)&b3;
                *reinterpret_cast<ushort4*>(wb + c0 + lane*4) = pk;
                ss += wv.x*av.x + wv.y*av.y + wv.z*av.z + wv.w*av.w;
                sd += wv.x*dv.x + wv.y*dv.y + wv.z*dv.z + wv.w*dv.w;
            }
            #pragma unroll
            for (int off=32; off; off>>=1){
                ss += __shfl_down(ss, off);
                sd += __shfl_down(sd, off);
            }
            if (lane == 0){
                v[k*16 + hh]     = ss;
                v[k*16 + 8 + hh] = sd;
            }
        }
    } else if (bid == VSRC_NB){
        // zero cursors (NN ints, NN % 4 == 0)
        for (int i = tid*4; i < NN; i += 1024){
            int4 z; z.x = z.y = z.z = z.w = 0;
            *reinterpret_cast<int4*>(cursors + i) = z;
        }
    } else {
        // ---- W_lin transpose + beff partials: block owns c-rows [b*32, b*32+32) ----
        int b = bid - TRN_BASE;          // 0..127
        if (tid < 32) bg_s[tid] = b_gat[b*32 + tid];
        for (int sub = 0; sub < 4; ++sub){
            __syncthreads();             // prev tile use complete (also publishes bg_s)
            #pragma unroll
            for (int u = 0; u < 4; ++u){
                int f = tid + 256*u;     // 0..1023
                int row = f >> 5;        // c_local 0..31
                int cq  = f & 31;        // float4 group
                float4 vv = *(const float4*)(W_lin + (size_t)(b*32+row)*NOUT + sub*128 + cq*4);
                *(float4*)&tl[row][cq*4] = vv;
            }
            __syncthreads();
            if (tid < 128){
                float a = 0.f;
                #pragma unroll
                for (int c = 0; c < 32; ++c) a = fmaf(bg_s[c], tl[c][tid], a);
                beff_part[(size_t)b*NOUT + sub*128 + tid] = a;
            }
            {
                int o_loc = tid >> 1, half = tid & 1;
                unsigned int us[8];
                #pragma unroll
                for (int k = 0; k < 8; ++k){
                    float v0 = tl[half*16 + 2*k][o_loc];
                    float v1 = tl[half*16 + 2*k + 1][o_loc];
                    bf16 b0 = __float2bfloat16(v0), b1 = __float2bfloat16(v1);
                    us[k] = (unsigned int)*(unsigned short*)&b0
                          | ((unsigned int)*(unsigned short*)&b1 << 16);
                }
                bf16* dst = WlT + (size_t)(sub*128 + o_loc)*HC + b*32 + half*16;
                *(uint4*)(dst)     = *(uint4*)&us[0];
                *(uint4*)(dst + 8) = *(uint4*)&us[4];
            }
        }
    }
}

// ================= phase B =================
// [0,64):   Wc GEMM: D[k'][o] = sum_c Wg[k'][h*512+c]*WlT[o][h*512+c] -> WcT[o][h*128+k']
//           (pure gld_lds staging, dbuf, 2-bit XOR swizzle both sides)
// [64,346): edge bucket fill
// 346:      beff[o] = sum_b beff_part[b][o]
// [347,847): attn2
__global__ __launch_bounds__(256) void k_phaseB(
    const bf16* __restrict__ Wg, const bf16* __restrict__ WlT,
    const int* __restrict__ eidx,
    bf16* __restrict__ WcT,
    const float* __restrict__ beff_part, float* __restrict__ beff,
    int* __restrict__ cursors, int* __restrict__ esrc,
    const float* __restrict__ x, const float* __restrict__ v,
    float* __restrict__ a_src, float* __restrict__ a_dst)
{
    __shared__ __align__(16) char smem_raw[24576];
    const int bid = blockIdx.x;
    const int tid = threadIdx.x;

    if (bid < PB_GEMM_NB){
        bf16* sA = (bf16*)smem_raw;               // [2][64*32]  = 8 KB
        bf16* sB = (bf16*)smem_raw + 2*64*32;     // [2][128*32] = 16 KB

        const int head = bid >> 3;
        const int rem  = bid & 7;
        const int m0   = (rem >> 2) * 64;      // k'-tile: 0,64
        const int n0   = (rem & 3) * 128;      // o-tile
        const int lane = tid & 63;
        const int w = tid >> 6, wm = w >> 1, wn = w & 1;
        const int m16 = lane & 15, q = lane >> 4;

        // A staging: 256 chunks (64 rows x 4), source-swizzled
        const int rA = tid >> 2, jA = (tid & 3) ^ (rA & 3);
        const bf16* Asrc = Wg + (size_t)(m0 + rA)*HC + head*OC + jA*8;
        // B staging: 512 chunks (128 rows x 4), 2 per thread
        const int rB0 = tid >> 2,         jB0 = (tid & 3) ^ (rB0 & 3);
        const int rB1 = (tid + 256) >> 2, jB1 = ((tid + 256) & 3) ^ (rB1 & 3);
        const bf16* Bsrc0 = WlT + (size_t)(n0 + rB0)*HC + head*OC + jB0*8;
        const bf16* Bsrc1 = WlT + (size_t)(n0 + rB1)*HC + head*OC + jB1*8;

        f32x4 acc[2][4];
        #pragma unroll
        for (int i=0;i<2;++i)
            #pragma unroll
            for (int j=0;j<4;++j)
                #pragma unroll
                for (int r=0;r<4;++r) acc[i][j][r] = 0.f;

        gld_lds16(Asrc,  sA + tid*8);
        gld_lds16(Bsrc0, sB + tid*8);
        gld_lds16(Bsrc1, sB + (tid+256)*8);
        __syncthreads();

        const int nIter = OC / 32;   // 16
        for (int it = 0; it < nIter; ++it){
            const int cur = it & 1, nxt = cur ^ 1;
            bf16x8 af[2], bfr[4];
            #pragma unroll
            for (int i=0;i<2;++i){
                int row = wm*32 + i*16 + m16;
                int p   = q ^ (row & 3);
                af[i] = *(const bf16x8*)(const void*)(sA + cur*64*32 + row*32 + p*8);
            }
            #pragma unroll
            for (int j=0;j<4;++j){
                int row = wn*64 + j*16 + m16;
                int p   = q ^ (row & 3);
                bfr[j] = *(const bf16x8*)(const void*)(sB + cur*128*32 + row*32 + p*8);
            }
            if (it + 1 < nIter){
                int ko = (it+1) * 32;
                gld_lds16(Asrc  + ko, sA + nxt*64*32 + tid*8);
                gld_lds16(Bsrc0 + ko, sB + nxt*128*32 + tid*8);
                gld_lds16(Bsrc1 + ko, sB + nxt*128*32 + (tid+256)*8);
            }
            #pragma unroll
            for (int i=0;i<2;++i)
                #pragma unroll
                for (int j=0;j<4;++j)
                    acc[i][j] = __builtin_amdgcn_mfma_f32_16x16x32_bf16(af[i], bfr[j], acc[i][j], 0, 0, 0);
            __syncthreads();
        }

        #pragma unroll
        for (int i=0;i<2;++i){
            int row_base = m0 + wm*32 + i*16 + q*4;
            #pragma unroll
            for (int j=0;j<4;++j){
                int col = n0 + wn*64 + j*16 + m16;
                ushort4 pk;
                bf16 b0 = __float2bfloat16(acc[i][j][0]);
                bf16 b1 = __float2bfloat16(acc[i][j][1]);
                bf16 b2 = __float2bfloat16(acc[i][j][2]);
                bf16 b3 = __float2bfloat16(acc[i][j][3]);
                pk.x = *(unsigned short*)&b0; pk.y = *(unsigned short*)&b1;
                pk.z = *(unsigned short*)&b2; pk.w = *(unsigned short*)&b3;
                *reinterpret_cast<ushort4*>(WcT + (size_t)col*YW + head*KIN + row_base) = pk;
            }
        }
        return;
    }

    if (bid < RED_BID){
        // ---- edge bucket fill ----
        int e = (bid - FILL_BASE)*256 + tid;
        if (e < NE2){
            int src, dst;
            if (e < NE){ src = eidx[e]; dst = eidx[NE+e]; } else { src = dst = e - NE; }
            int pos = atomicAdd(&cursors[dst], 1);
            if (pos < MAXDEG) esrc[dst*MAXDEG + pos] = src;
        }
        return;
    }

    if (bid == RED_BID){
        // ---- beff reduce: 256 threads x 2 cols ----
        int o = tid * 2;
        float s0 = 0.f, s1 = 0.f;
        for (int b = 0; b < 128; ++b){
            float2 vv = *(const float2*)(beff_part + (size_t)b*NOUT + o);
            s0 += vv.x; s1 += vv.y;
        }
        beff[o] = s0; beff[o+1] = s1;
        return;
    }

    // ---- attn2 ----
    float (*xs)[132] = (float(*)[132])smem_raw;
    float (*vt)[132] = (float(*)[132])(smem_raw + 16*132*4);
    int node0 = (bid - ATT_BASE) * 16;
    {
        const float* xg = x + (size_t)node0*KIN;
        int row = tid >> 4, co = (tid & 15) * 8;
        float4 v0 = *(const float4*)(xg + row*KIN + co);
        float4 v1 = *(const float4*)(xg + row*KIN + co + 4);
        *(float4*)&xs[row][co]     = v0;
        *(float4*)&xs[row][co + 4] = v1;
    }
    {
        int base = tid*8;
        #pragma unroll
        for (int j=0;j<8;++j){
            int idx = base + j;
            vt[idx & 15][idx >> 4] = v[idx];
        }
    }
    __syncthreads();
    int ln = tid >> 4, o = tid & 15;
    float acc = 0.f;
    #pragma unroll
    for (int k0=0;k0<KIN;k0+=4){
        float4 xv = *(const float4*)&xs[ln][k0];
        float4 vv = *(const float4*)&vt[o][k0];
        acc += xv.x*vv.x + xv.y*vv.y + xv.z*vv.z + xv.w*vv.w;
    }
    int node = node0 + ln;
    if (o < 8) a_src[node*NH + o]     = acc;
    else       a_dst[node*NH + o - 8] = acc;
}

// ================= Y aggregation (reg-cached bucket; UNIFORM trip counts for shfl) =========
__global__ __launch_bounds__(256) void k_agg(const int* __restrict__ cnts,
    const int* __restrict__ esrc, const float* __restrict__ a_src,
    const float* __restrict__ a_dst, const float* __restrict__ x,
    bf16* __restrict__ Y)
{
    int node = blockIdx.x*4 + (threadIdx.x >> 6);
    int lane = threadIdx.x & 63;
    int cnt = min(cnts[node], MAXDEG);     // wave-uniform (one node per wave)
    int s0 = node*MAXDEG;
    // cache the whole bucket: lane l holds esrc[s0+l] (clamped dup for l>=cnt)
    int my_src = esrc[s0 + min(lane, cnt-1)];
    int g = lane >> 3, h = lane & 7;
    float adl = a_dst[node*NH + h];
    float m = -1e30f, sum = 0.f;
    // pass 1: UNIFORM iteration count across all 64 lanes so every __shfl
    // executes with the full wave active (divergent-shfl was round-8's bug).
    int iters = (cnt + 7) >> 3;
    for (int t = 0; t < iters; ++t){
        int idx = g + t*8;
        int src = __shfl(my_src, min(idx, cnt-1));   // all lanes active; valid src lane
        if (idx < cnt){
            float l = a_src[src*NH + h] + adl;
            l = l > 0.f ? l : NEG_SLOPE*l;
            float mn = fmaxf(m, l);
            sum = sum*__expf(m - mn) + __expf(l - mn);
            m = mn;
        }
    }
    #pragma unroll
    for (int d=8; d<64; d<<=1){
        float mo = __shfl_xor(m, d);
        float so = __shfl_xor(sum, d);
        float mn = fmaxf(m, mo);
        sum = sum*__expf(m - mn) + so*__expf(mo - mn);
        m = mn;
    }
    float inv = 1.f / (sum + 1e-16f);
    float acc[16];
    #pragma unroll
    for (int j=0;j<16;++j) acc[j] = 0.f;

    // pass 2: uniform trips (cnt wave-uniform), 2-deep pipeline, esrc via shfl
    int src_n = __shfl(my_src, 0);
    float2 xv_n = *(const float2*)(x + (size_t)src_n*KIN + lane*2);
    float al_n = (lane < 8) ? a_src[src_n*NH + lane] : 0.f;
    for (int s = 0; s < cnt; ++s){
        float2 xv = xv_n;
        float al = al_n;
        if (s + 1 < cnt){
            int sn = __shfl(my_src, s + 1);
            xv_n = *(const float2*)(x + (size_t)sn*KIN + lane*2);
            al_n = (lane < 8) ? a_src[sn*NH + lane] : 0.f;
        }
        float wl = 0.f;
        if (lane < 8){
            float l = al + adl;
            l = l > 0.f ? l : NEG_SLOPE*l;
            wl = __expf(l - m) * inv;
        }
        #pragma unroll
        for (int hh=0; hh<8; ++hh){
            float wh = __shfl(wl, hh);
            acc[hh*2]   = fmaf(wh, xv.x, acc[hh*2]);
            acc[hh*2+1] = fmaf(wh, xv.y, acc[hh*2+1]);
        }
    }
    bf16* yp = Y + (size_t)node*YW + lane*2;
    #pragma unroll
    for (int hh=0; hh<8; ++hh){
        bf16 b0 = __float2bfloat16(acc[hh*2]);
        bf16 b1 = __float2bfloat16(acc[hh*2+1]);
        ushort2 pk;
        pk.x = *(unsigned short*)&b0;
        pk.y = *(unsigned short*)&b1;
        *reinterpret_cast<ushort2*>(yp + hh*KIN) = pk;
    }
}

// ================= final GEMM: out = Y @ WcT^T + beff + b_lin ===
__global__ __launch_bounds__(256) void k_gemm64(
    const bf16* __restrict__ A, const bf16* __restrict__ BT,
    const float* __restrict__ beff, const float* __restrict__ b_lin,
    float* __restrict__ C)
{
    __shared__ __align__(16) bf16 sA[2*64*64];    // 16 KB
    __shared__ __align__(16) bf16 sB[2*128*64];   // 32 KB
    const int tid = threadIdx.x;

    const int orig = blockIdx.x;
    const int xcd = orig & 7, slot = orig >> 3;
    const int wgid = (xcd < 4 ? xcd*63 : 252 + (xcd-4)*62) + slot;
    const int m0 = (wgid >> 2) * 64;
    const int n0 = (wgid & 3) * 128;

    Acc24 acc;
    gemm64x128_bk64(A + (size_t)m0*YW, YW, BT + (size_t)n0*YW, YW, YW, sA, sB, tid, acc);

    const int lane = tid & 63;
    const int w = tid >> 6, wm = w >> 1, wn = w & 1;
    const int m16 = lane & 15, q = lane >> 4;
    #pragma unroll
    for (int j=0;j<4;++j){
        int col = n0 + wn*64 + j*16 + m16;
        float bval = beff[col] + b_lin[col];
        #pragma unroll
        for (int i=0;i<2;++i){
            int row_base = m0 + wm*32 + i*16 + q*4;
            #pragma unroll
            for (int r=0;r<4;++r)
                C[(size_t)(row_base + r)*NOUT + col] = acc.a[i][j][r] + bval;
        }
    }
}

extern "C" void kernel_launch(void* const* d_in, const int* in_sizes, int n_in,
                              void* d_out, int out_size, void* d_ws, size_t ws_size,
                              hipStream_t stream)
{
    const float* x       = (const float*)d_in[0];
    const int*   eidx    = (const int*)  d_in[1];
    const float* W_gat   = (const float*)d_in[2];
    const float* b_gat   = (const float*)d_in[3];
    const float* att_src = (const float*)d_in[4];
    const float* att_dst = (const float*)d_in[5];
    const float* W_lin   = (const float*)d_in[6];
    const float* b_lin   = (const float*)d_in[7];
    float* out = (float*)d_out;

    char* p = (char*)d_ws;
    auto alloc = [&](size_t bytes){ void* r = (void*)p; p += (bytes + 255) & ~(size_t)255; return r; };
    bf16*  Wg        = (bf16*) alloc((size_t)KIN*HC*2);      // 1 MB
    bf16*  WlT       = (bf16*) alloc((size_t)NOUT*HC*2);     // 4 MB
    bf16*  WcT       = (bf16*) alloc((size_t)NOUT*YW*2);     // 1 MB
    bf16*  Ybuf      = (bf16*) alloc((size_t)NN*YW*2);       // 16.4 MB
    float* v         = (float*)alloc((size_t)KIN*16*4);
    float* a_src     = (float*)alloc((size_t)NN*NH*4);
    float* a_dst     = (float*)alloc((size_t)NN*NH*4);
    int*   esrc      = (int*)  alloc((size_t)NN*MAXDEG*4);   // 2 MB
    int*   cursors   = (int*)  alloc((size_t)NN*4);
    float* beff_part = (float*)alloc((size_t)128*NOUT*4);    // 256 KB
    float* beff      = (float*)alloc((size_t)NOUT*4);
    if ((size_t)(p - (char*)d_ws) > ws_size) return;

    k_phaseA<<<PHA_NB, 256, 0, stream>>>(W_gat, att_src, att_dst, W_lin, b_gat,
                                         Wg, v, WlT, beff_part, cursors);
    k_phaseB<<<PHB_NB, 256, 0, stream>>>(Wg, WlT, eidx, WcT, beff_part, beff,
                                         cursors, esrc, x, v, a_src, a_dst);
    k_agg<<<NN/4, 256, 0, stream>>>(cursors, esrc, a_src, a_dst, x, Ybuf);
    k_gemm64<<<GEMM_NB, 256, 0, stream>>>(Ybuf, WcT, beff, b_lin, out);
}